// Round 7
// baseline (409.954 us; speedup 1.0000x reference)
//
#include <hip/hip_runtime.h>
#include <hip/hip_bf16.h>

#define M_TOTAL (32 * 64 * 64)   // 131072 rows
#define CDIM 256
#define HDIM 1024

typedef float  floatx4 __attribute__((ext_vector_type(4)));
typedef short  short8  __attribute__((ext_vector_type(8)));

// ---------------------------------------------------------------------------
// transpose + fp32->bf16 convert.  src[R][Cc] f32 -> dst[Cc][R] bf16
// ---------------------------------------------------------------------------
__global__ __launch_bounds__(256) void transpose_cvt(
    const float* __restrict__ src, __hip_bfloat16* __restrict__ dst,
    int R, int Cc)
{
    const int idx = blockIdx.x * 256 + threadIdx.x;   // idx = c*R + r
    const int r = idx % R;
    const int c = idx / R;
    dst[idx] = __float2bfloat16(src[(long)r * Cc + c]);
}

// fast GELU (tanh form), max dev vs erf-GELU ~1e-3 (validated: absmax 0.0625)
__device__ __forceinline__ float gelu_fast(float v)
{
    const float t = v * __builtin_fmaf(v * v, 0.044715f, 1.0f);
    const float e = __expf(t * -1.5957691216f);
    return v * __builtin_amdgcn_rcpf(1.0f + e);
}

// ---------------------------------------------------------------------------
// Fully fused Swin block (attention path = identity), software-pipelined with
// register-budget discipline:
//   - __launch_bounds__(512,2): LDS (128KB) already limits to 2 waves/SIMD;
//     tell the allocator so it uses the full 256-VGPR budget instead of
//     spilling the weight bursts to scratch (the R4-R6 400us plateau).
//   - schedule: LOADB1(c); FC2(c-1); FC1(c); LOADB2(c); GELU(c); bar
//     b1f latency hides under FC2 (64 MFMA); b2f under GELU (~600cy VALU).
//     Max live set: b2f(c-1)+b1f(c)+acc2 = 232 VGPR < 256.
//   - sched_barrier(0) after each burst pins the loads.
// LDS: As 64KB + Hs 2x32KB = 128KB, 1 block/CU, 8 waves (2 rg x 4 cg).
// Verified conventions (R1-R6): frag k-map slot=kf*4+fq, elem k&7, row/col=fr;
// C/D: col=lane&15, row=(lane>>4)*4+reg.
// ---------------------------------------------------------------------------
__global__ __launch_bounds__(512, 2) void swin_fused(
    const float* __restrict__ x,
    const float* __restrict__ ln1g, const float* __restrict__ ln1b,
    const float* __restrict__ ln2g, const float* __restrict__ ln2b,
    const __hip_bfloat16* __restrict__ w1t, const float* __restrict__ fb1,
    const __hip_bfloat16* __restrict__ w2t, const float* __restrict__ fb2,
    __hip_bfloat16* __restrict__ xnbuf, float* __restrict__ out)
{
    __shared__ __align__(16) __hip_bfloat16 As[32768];      // 64 KB
    __shared__ __align__(16) __hip_bfloat16 Hs[2][16384];   // 2 x 32 KB

    const int  tid = threadIdx.x;
    const long m0  = (long)blockIdx.x * 128;

    // ---------------- LN phase: 4 threads per row ----------------
    {
        const int row  = tid >> 2;        // 0..127
        const int part = tid & 3;         // 64-element segment
        const float* xr = x + (m0 + row) * CDIM + part * 64;

        float4 v[16];
        float s = 0.f, sq = 0.f;
#pragma unroll
        for (int i = 0; i < 16; ++i) {
            v[i] = ((const float4*)xr)[i];
            s  += v[i].x + v[i].y + v[i].z + v[i].w;
            sq += v[i].x*v[i].x + v[i].y*v[i].y + v[i].z*v[i].z + v[i].w*v[i].w;
        }
        s  += __shfl_xor(s, 1);  s  += __shfl_xor(s, 2);
        sq += __shfl_xor(sq, 1); sq += __shfl_xor(sq, 2);
        const float mu = s * (1.f / CDIM);
        const float rs = rsqrtf(sq * (1.f / CDIM) - mu * mu + 1e-5f);

        float s2 = 0.f, q2 = 0.f;
        __hip_bfloat16* xnp = xnbuf + (m0 + row) * CDIM + part * 64;
#pragma unroll
        for (int i = 0; i < 16; ++i) {
            const float4 G = ((const float4*)(ln1g + part * 64))[i];
            const float4 B = ((const float4*)(ln1b + part * 64))[i];
            v[i].x += (v[i].x - mu) * rs * G.x + B.x;
            v[i].y += (v[i].y - mu) * rs * G.y + B.y;
            v[i].z += (v[i].z - mu) * rs * G.z + B.z;
            v[i].w += (v[i].w - mu) * rs * G.w + B.w;
            s2 += v[i].x + v[i].y + v[i].z + v[i].w;
            q2 += v[i].x*v[i].x + v[i].y*v[i].y + v[i].z*v[i].z + v[i].w*v[i].w;
            union { ushort4 u; __hip_bfloat16 h[4]; } p;
            p.h[0] = __float2bfloat16(v[i].x); p.h[1] = __float2bfloat16(v[i].y);
            p.h[2] = __float2bfloat16(v[i].z); p.h[3] = __float2bfloat16(v[i].w);
            ((ushort4*)xnp)[i] = p.u;
        }
        s2 += __shfl_xor(s2, 1); s2 += __shfl_xor(s2, 2);
        q2 += __shfl_xor(q2, 1); q2 += __shfl_xor(q2, 2);
        const float mu2 = s2 * (1.f / CDIM);
        const float rs2 = rsqrtf(q2 * (1.f / CDIM) - mu2 * mu2 + 1e-5f);

        // ln2 -> As fragment layout: slot=(k>>5)*4+((k>>3)&3), elem k&7
#pragma unroll
        for (int i = 0; i < 16; ++i) {
            const int col0 = part * 64 + i * 4;
            const float4 G = ((const float4*)(ln2g + part * 64))[i];
            const float4 B = ((const float4*)(ln2b + part * 64))[i];
            union { ushort4 u; __hip_bfloat16 h[4]; } p;
            p.h[0] = __float2bfloat16((v[i].x - mu2) * rs2 * G.x + B.x);
            p.h[1] = __float2bfloat16((v[i].y - mu2) * rs2 * G.y + B.y);
            p.h[2] = __float2bfloat16((v[i].z - mu2) * rs2 * G.z + B.z);
            p.h[3] = __float2bfloat16((v[i].w - mu2) * rs2 * G.w + B.w);
            const int idx16 = ((col0 >> 5) * 4 + ((col0 >> 3) & 3)) * 128 + row;
            *(ushort4*)(As + idx16 * 8 + (col0 & 7)) = p.u;
        }
    }
    __syncthreads();

    // ---------------- MLP phase (8 chunks of 128 hidden cols) -------------
    const int wave = tid >> 6, lane = tid & 63;
    const int wm = wave >> 2, wn = wave & 3;   // 2 row-groups x 4 col-groups
    const int fr = lane & 15, fq = lane >> 4;

    floatx4 acc2[4][4] = {};
    floatx4 acc1[4][2];
    short8 b1f[8][2];   // fc1 weight frags: 64 VGPR
    short8 b2f[4][4];   // fc2 weight frags: 64 VGPR

    const __hip_bfloat16* w1base = w1t + (wn * 32 + fr) * 256 + fq * 8;
    const __hip_bfloat16* w2base = w2t + (wn * 64 + fr) * 1024 + fq * 8;

#define LOADB1(c)                                                             \
    {                                                                         \
        const __hip_bfloat16* p = w1base + (c) * 128 * 256;                   \
        _Pragma("unroll")                                                     \
        for (int kf = 0; kf < 8; ++kf)                                        \
            _Pragma("unroll")                                                 \
            for (int nf = 0; nf < 2; ++nf)                                    \
                b1f[kf][nf] = *(const short8*)(p + nf * 16 * 256 + kf * 32);  \
        __builtin_amdgcn_sched_barrier(0);                                    \
    }
#define LOADB2(c)                                                             \
    {                                                                         \
        const __hip_bfloat16* p = w2base + (c) * 128;                         \
        _Pragma("unroll")                                                     \
        for (int kf = 0; kf < 4; ++kf)                                        \
            _Pragma("unroll")                                                 \
            for (int nf = 0; nf < 4; ++nf)                                    \
                b2f[kf][nf] = *(const short8*)(p + nf * 16 * 1024 + kf * 32); \
        __builtin_amdgcn_sched_barrier(0);                                    \
    }

    // fc1: rows wm*64..+64 (mf=4), chunk cols wn*32..+32 (nf=2), K=256 (kf=8)
#define FC1(c)                                                                \
    {                                                                         \
        _Pragma("unroll")                                                     \
        for (int mf = 0; mf < 4; ++mf)                                        \
            _Pragma("unroll")                                                 \
            for (int nf = 0; nf < 2; ++nf)                                    \
                acc1[mf][nf] = (floatx4){0.f, 0.f, 0.f, 0.f};                 \
        _Pragma("unroll")                                                     \
        for (int kf = 0; kf < 8; ++kf) {                                      \
            short8 a[4];                                                      \
            _Pragma("unroll")                                                 \
            for (int mf = 0; mf < 4; ++mf)                                    \
                a[mf] = *(const short8*)(                                     \
                    As + ((kf * 4 + fq) * 128 + wm * 64 + mf * 16 + fr) * 8); \
            _Pragma("unroll")                                                 \
            for (int mf = 0; mf < 4; ++mf)                                    \
                _Pragma("unroll")                                             \
                for (int nf = 0; nf < 2; ++nf)                                \
                    acc1[mf][nf] = __builtin_amdgcn_mfma_f32_16x16x32_bf16(   \
                        a[mf], b1f[kf][nf], acc1[mf][nf], 0, 0, 0);           \
        }                                                                     \
    }

    // GELU + bias on acc1 -> Hs[(c)&1] (fragment layout, in-chunk col)
#define GELU_STORE(c)                                                         \
    {                                                                         \
        __hip_bfloat16* hb = Hs[(c) & 1];                                     \
        _Pragma("unroll")                                                     \
        for (int nf = 0; nf < 2; ++nf) {                                      \
            const int   col = wn * 32 + nf * 16 + fr;                         \
            const float bb  = fb1[(c) * 128 + col];                           \
            __hip_bfloat16* hp =                                              \
                hb + (((col >> 5) * 4 + ((col >> 3) & 3)) * 128) * 8 + (col & 7); \
            _Pragma("unroll")                                                 \
            for (int mf = 0; mf < 4; ++mf)                                    \
                _Pragma("unroll")                                             \
                for (int j = 0; j < 4; ++j) {                                 \
                    const int row = wm * 64 + mf * 16 + fq * 4 + j;           \
                    hp[row * 8] =                                             \
                        __float2bfloat16(gelu_fast(acc1[mf][nf][j] + bb));    \
                }                                                             \
        }                                                                     \
    }

    // fc2: rows wm*64..+64 (mf=4), out cols wn*64..+64 (nf=4), chunk K=128 (kf=4)
#define FC2(c)                                                                \
    {                                                                         \
        const __hip_bfloat16* hb = Hs[(c) & 1];                               \
        _Pragma("unroll")                                                     \
        for (int kf = 0; kf < 4; ++kf) {                                      \
            short8 ha[4];                                                     \
            _Pragma("unroll")                                                 \
            for (int mf = 0; mf < 4; ++mf)                                    \
                ha[mf] = *(const short8*)(                                    \
                    hb + ((kf * 4 + fq) * 128 + wm * 64 + mf * 16 + fr) * 8); \
            _Pragma("unroll")                                                 \
            for (int mf = 0; mf < 4; ++mf)                                    \
                _Pragma("unroll")                                             \
                for (int nf = 0; nf < 4; ++nf)                                \
                    acc2[mf][nf] = __builtin_amdgcn_mfma_f32_16x16x32_bf16(   \
                        ha[mf], b2f[kf][nf], acc2[mf][nf], 0, 0, 0);          \
        }                                                                     \
    }

    // prologue: chunk 0
    LOADB1(0);
    FC1(0);
    LOADB2(0);          // b2f(0) in flight during GELU's VALU work
    GELU_STORE(0);
    __syncthreads();

#pragma unroll 1
    for (int c = 1; c < 8; ++c) {
        LOADB1(c);      // b1f(c) in flight during FC2(c-1)'s 64 MFMA
        FC2(c - 1);
        FC1(c);
        LOADB2(c);      // b2f(c) in flight during GELU
        GELU_STORE(c);
        __syncthreads();
    }
    FC2(7);

    // ---------------- epilogue: out = acc2 + b2 + xn ----------------
#pragma unroll
    for (int nf = 0; nf < 4; ++nf) {
        const int   oc = wn * 64 + nf * 16 + fr;
        const float bb = fb2[oc];
#pragma unroll
        for (int mf = 0; mf < 4; ++mf)
#pragma unroll
            for (int j = 0; j < 4; ++j) {
                const long row = m0 + wm * 64 + mf * 16 + fq * 4 + j;
                out[row * CDIM + oc] = acc2[mf][nf][j] + bb
                                     + __bfloat162float(xnbuf[row * CDIM + oc]);
            }
    }
#undef LOADB1
#undef LOADB2
#undef FC1
#undef GELU_STORE
#undef FC2
}

// ---------------------------------------------------------------------------
extern "C" void kernel_launch(void* const* d_in, const int* in_sizes, int n_in,
                              void* d_out, int out_size, void* d_ws, size_t ws_size,
                              hipStream_t stream)
{
    const float* x    = (const float*)d_in[0];
    const float* ln1g = (const float*)d_in[1];
    const float* ln1b = (const float*)d_in[2];
    const float* ln2g = (const float*)d_in[3];
    const float* ln2b = (const float*)d_in[4];
    const float* w1   = (const float*)d_in[5];
    const float* b1   = (const float*)d_in[6];
    const float* w2   = (const float*)d_in[7];
    const float* b2   = (const float*)d_in[8];
    float* out = (float*)d_out;

    // workspace
    char* ws = (char*)d_ws;
    __hip_bfloat16* xnbuf = (__hip_bfloat16*)ws;                 //  67,108,864 B
    __hip_bfloat16* w1t   = (__hip_bfloat16*)(ws + 67108864);    //     524,288 B
    __hip_bfloat16* w2t   = (__hip_bfloat16*)(ws + 67633152);    //     524,288 B

    // weight transpose + bf16 convert (w1t[1024][256], w2t[256][1024])
    transpose_cvt<<<(CDIM * HDIM) / 256, 256, 0, stream>>>(w1, w1t, CDIM, HDIM);
    transpose_cvt<<<(CDIM * HDIM) / 256, 256, 0, stream>>>(w2, w2t, HDIM, CDIM);

    // fully fused block
    swin_fused<<<M_TOTAL / 128, 512, 0, stream>>>(
        x, ln1g, ln1b, ln2g, ln2b, w1t, b1, w2t, b2, xnbuf, out);
}

// Round 8
// 361.808 us; speedup vs baseline: 1.1331x; 1.1331x over previous
//
#include <hip/hip_runtime.h>
#include <hip/hip_bf16.h>

#define M_TOTAL (32 * 64 * 64)   // 131072 rows
#define CDIM 256
#define HDIM 1024

typedef float  floatx4 __attribute__((ext_vector_type(4)));
typedef short  short8  __attribute__((ext_vector_type(8)));

// ---------------------------------------------------------------------------
// transpose + fp32->bf16 convert.  src[R][Cc] f32 -> dst[Cc][R] bf16
// ---------------------------------------------------------------------------
__global__ __launch_bounds__(256) void transpose_cvt(
    const float* __restrict__ src, __hip_bfloat16* __restrict__ dst,
    int R, int Cc)
{
    const int idx = blockIdx.x * 256 + threadIdx.x;   // idx = c*R + r
    const int r = idx % R;
    const int c = idx / R;
    dst[idx] = __float2bfloat16(src[(long)r * Cc + c]);
}

// fast GELU (tanh form), max dev vs erf-GELU ~1e-3 (validated: absmax 0.0625)
__device__ __forceinline__ float gelu_fast(float v)
{
    const float t = v * __builtin_fmaf(v * v, 0.044715f, 1.0f);
    const float e = __expf(t * -1.5957691216f);
    return v * __builtin_amdgcn_rcpf(1.0f + e);
}

// ---------------------------------------------------------------------------
// Fully fused Swin block (attention path = identity).
// R8 change: M-tile 128 -> 64 rows, 4 waves, LDS 64KB -> TWO independent
// blocks per CU (R4-R7 plateau was 1 block/CU = one barrier domain = no
// latency hiding; m114 mechanism needs co-resident independent blocks).
//   xn  = x + LN1(x)  (bf16 -> xnbuf) ;  ln2 = LN2(xn) (bf16 -> LDS As)
//   8 hidden chunks of 128:
//     LOADB1(c); FC2(c-1); FC1(c); LOADB2(c); GELU(c); barrier
//   out = xn + acc2 + b2
// LDS: As 32KB ([slot 0..31][row 0..63][8]) + Hs 2 x 16KB ([slot 0..15]...).
// Per-wave: rows 0..63 (mf=4), fc1 cols wn*32+nf*16 (nf=2), fc2 out cols
// wn*64+nf*16 (nf=4).  Frag conventions verified R1-R7:
//   A/B k-map: slot=kf*4+fq, elem k&7, row/col=fr;  C/D: col=lane&15,
//   row=(lane>>4)*4+reg.
// ---------------------------------------------------------------------------
__global__ __launch_bounds__(256, 2) void swin_fused(
    const float* __restrict__ x,
    const float* __restrict__ ln1g, const float* __restrict__ ln1b,
    const float* __restrict__ ln2g, const float* __restrict__ ln2b,
    const __hip_bfloat16* __restrict__ w1t, const float* __restrict__ fb1,
    const __hip_bfloat16* __restrict__ w2t, const float* __restrict__ fb2,
    __hip_bfloat16* __restrict__ xnbuf, float* __restrict__ out)
{
    __shared__ __align__(16) __hip_bfloat16 As[16384];      // 32 KB
    __shared__ __align__(16) __hip_bfloat16 Hs[2][8192];    // 2 x 16 KB

    const int  tid = threadIdx.x;
    const long m0  = (long)blockIdx.x * 64;

    // ---------------- LN phase: 4 threads per row ----------------
    {
        const int row  = tid >> 2;        // 0..63
        const int part = tid & 3;         // 64-element segment
        const float* xr = x + (m0 + row) * CDIM + part * 64;

        float4 v[16];
        float s = 0.f, sq = 0.f;
#pragma unroll
        for (int i = 0; i < 16; ++i) {
            v[i] = ((const float4*)xr)[i];
            s  += v[i].x + v[i].y + v[i].z + v[i].w;
            sq += v[i].x*v[i].x + v[i].y*v[i].y + v[i].z*v[i].z + v[i].w*v[i].w;
        }
        s  += __shfl_xor(s, 1);  s  += __shfl_xor(s, 2);
        sq += __shfl_xor(sq, 1); sq += __shfl_xor(sq, 2);
        const float mu = s * (1.f / CDIM);
        const float rs = rsqrtf(sq * (1.f / CDIM) - mu * mu + 1e-5f);

        float s2 = 0.f, q2 = 0.f;
        __hip_bfloat16* xnp = xnbuf + (m0 + row) * CDIM + part * 64;
#pragma unroll
        for (int i = 0; i < 16; ++i) {
            const float4 G = ((const float4*)(ln1g + part * 64))[i];
            const float4 B = ((const float4*)(ln1b + part * 64))[i];
            v[i].x += (v[i].x - mu) * rs * G.x + B.x;
            v[i].y += (v[i].y - mu) * rs * G.y + B.y;
            v[i].z += (v[i].z - mu) * rs * G.z + B.z;
            v[i].w += (v[i].w - mu) * rs * G.w + B.w;
            s2 += v[i].x + v[i].y + v[i].z + v[i].w;
            q2 += v[i].x*v[i].x + v[i].y*v[i].y + v[i].z*v[i].z + v[i].w*v[i].w;
            union { ushort4 u; __hip_bfloat16 h[4]; } p;
            p.h[0] = __float2bfloat16(v[i].x); p.h[1] = __float2bfloat16(v[i].y);
            p.h[2] = __float2bfloat16(v[i].z); p.h[3] = __float2bfloat16(v[i].w);
            ((ushort4*)xnp)[i] = p.u;
        }
        s2 += __shfl_xor(s2, 1); s2 += __shfl_xor(s2, 2);
        q2 += __shfl_xor(q2, 1); q2 += __shfl_xor(q2, 2);
        const float mu2 = s2 * (1.f / CDIM);
        const float rs2 = rsqrtf(q2 * (1.f / CDIM) - mu2 * mu2 + 1e-5f);

        // ln2 -> As fragment layout: slot=(k>>5)*4+((k>>3)&3), elem k&7
#pragma unroll
        for (int i = 0; i < 16; ++i) {
            const int col0 = part * 64 + i * 4;
            const float4 G = ((const float4*)(ln2g + part * 64))[i];
            const float4 B = ((const float4*)(ln2b + part * 64))[i];
            union { ushort4 u; __hip_bfloat16 h[4]; } p;
            p.h[0] = __float2bfloat16((v[i].x - mu2) * rs2 * G.x + B.x);
            p.h[1] = __float2bfloat16((v[i].y - mu2) * rs2 * G.y + B.y);
            p.h[2] = __float2bfloat16((v[i].z - mu2) * rs2 * G.z + B.z);
            p.h[3] = __float2bfloat16((v[i].w - mu2) * rs2 * G.w + B.w);
            const int idx16 = ((col0 >> 5) * 4 + ((col0 >> 3) & 3)) * 64 + row;
            *(ushort4*)(As + idx16 * 8 + (col0 & 7)) = p.u;
        }
    }
    __syncthreads();

    // ---------------- MLP phase (8 chunks of 128 hidden cols) -------------
    const int wn = tid >> 6;            // wave 0..3 = col-group
    const int lane = tid & 63;
    const int fr = lane & 15, fq = lane >> 4;

    floatx4 acc2[4][4] = {};
    floatx4 acc1[4][2];
    short8 b1f[8][2];   // fc1 weight frags
    short8 b2f[4][4];   // fc2 weight frags

    const __hip_bfloat16* w1base = w1t + (wn * 32 + fr) * 256 + fq * 8;
    const __hip_bfloat16* w2base = w2t + (wn * 64 + fr) * 1024 + fq * 8;

#define LOADB1(c)                                                             \
    {                                                                         \
        const __hip_bfloat16* p = w1base + (c) * 128 * 256;                   \
        _Pragma("unroll")                                                     \
        for (int kf = 0; kf < 8; ++kf)                                        \
            _Pragma("unroll")                                                 \
            for (int nf = 0; nf < 2; ++nf)                                    \
                b1f[kf][nf] = *(const short8*)(p + nf * 16 * 256 + kf * 32);  \
        __builtin_amdgcn_sched_barrier(0);                                    \
    }
#define LOADB2(c)                                                             \
    {                                                                         \
        const __hip_bfloat16* p = w2base + (c) * 128;                         \
        _Pragma("unroll")                                                     \
        for (int kf = 0; kf < 4; ++kf)                                        \
            _Pragma("unroll")                                                 \
            for (int nf = 0; nf < 4; ++nf)                                    \
                b2f[kf][nf] = *(const short8*)(p + nf * 16 * 1024 + kf * 32); \
        __builtin_amdgcn_sched_barrier(0);                                    \
    }

    // fc1: rows 0..63 (mf=4), chunk cols wn*32..+32 (nf=2), K=256 (kf=8)
#define FC1(c)                                                                \
    {                                                                         \
        _Pragma("unroll")                                                     \
        for (int mf = 0; mf < 4; ++mf)                                        \
            _Pragma("unroll")                                                 \
            for (int nf = 0; nf < 2; ++nf)                                    \
                acc1[mf][nf] = (floatx4){0.f, 0.f, 0.f, 0.f};                 \
        _Pragma("unroll")                                                     \
        for (int kf = 0; kf < 8; ++kf) {                                      \
            short8 a[4];                                                      \
            _Pragma("unroll")                                                 \
            for (int mf = 0; mf < 4; ++mf)                                    \
                a[mf] = *(const short8*)(                                     \
                    As + ((kf * 4 + fq) * 64 + mf * 16 + fr) * 8);            \
            _Pragma("unroll")                                                 \
            for (int mf = 0; mf < 4; ++mf)                                    \
                _Pragma("unroll")                                             \
                for (int nf = 0; nf < 2; ++nf)                                \
                    acc1[mf][nf] = __builtin_amdgcn_mfma_f32_16x16x32_bf16(   \
                        a[mf], b1f[kf][nf], acc1[mf][nf], 0, 0, 0);           \
        }                                                                     \
    }

    // GELU + bias on acc1 -> Hs[(c)&1] (fragment layout, in-chunk col)
#define GELU_STORE(c)                                                         \
    {                                                                         \
        __hip_bfloat16* hb = Hs[(c) & 1];                                     \
        _Pragma("unroll")                                                     \
        for (int nf = 0; nf < 2; ++nf) {                                      \
            const int   col = wn * 32 + nf * 16 + fr;                         \
            const float bb  = fb1[(c) * 128 + col];                           \
            __hip_bfloat16* hp =                                              \
                hb + (((col >> 5) * 4 + ((col >> 3) & 3)) * 64) * 8 + (col & 7); \
            _Pragma("unroll")                                                 \
            for (int mf = 0; mf < 4; ++mf)                                    \
                _Pragma("unroll")                                             \
                for (int j = 0; j < 4; ++j) {                                 \
                    const int row = mf * 16 + fq * 4 + j;                     \
                    hp[row * 8] =                                             \
                        __float2bfloat16(gelu_fast(acc1[mf][nf][j] + bb));    \
                }                                                             \
        }                                                                     \
    }

    // fc2: rows 0..63 (mf=4), out cols wn*64..+64 (nf=4), chunk K=128 (kf=4)
#define FC2(c)                                                                \
    {                                                                         \
        const __hip_bfloat16* hb = Hs[(c) & 1];                               \
        _Pragma("unroll")                                                     \
        for (int kf = 0; kf < 4; ++kf) {                                      \
            short8 ha[4];                                                     \
            _Pragma("unroll")                                                 \
            for (int mf = 0; mf < 4; ++mf)                                    \
                ha[mf] = *(const short8*)(                                    \
                    hb + ((kf * 4 + fq) * 64 + mf * 16 + fr) * 8);            \
            _Pragma("unroll")                                                 \
            for (int mf = 0; mf < 4; ++mf)                                    \
                _Pragma("unroll")                                             \
                for (int nf = 0; nf < 4; ++nf)                                \
                    acc2[mf][nf] = __builtin_amdgcn_mfma_f32_16x16x32_bf16(   \
                        ha[mf], b2f[kf][nf], acc2[mf][nf], 0, 0, 0);          \
        }                                                                     \
    }

    // prologue: chunk 0
    LOADB1(0);
    FC1(0);
    LOADB2(0);
    GELU_STORE(0);
    __syncthreads();

#pragma unroll 1
    for (int c = 1; c < 8; ++c) {
        LOADB1(c);      // b1f(c) in flight during FC2(c-1)
        FC2(c - 1);
        FC1(c);
        LOADB2(c);      // b2f(c) in flight during GELU
        GELU_STORE(c);
        __syncthreads();
    }
    FC2(7);

    // ---------------- epilogue: out = acc2 + b2 + xn ----------------
#pragma unroll
    for (int nf = 0; nf < 4; ++nf) {
        const int   oc = wn * 64 + nf * 16 + fr;
        const float bb = fb2[oc];
#pragma unroll
        for (int mf = 0; mf < 4; ++mf)
#pragma unroll
            for (int j = 0; j < 4; ++j) {
                const long row = m0 + mf * 16 + fq * 4 + j;
                out[row * CDIM + oc] = acc2[mf][nf][j] + bb
                                     + __bfloat162float(xnbuf[row * CDIM + oc]);
            }
    }
#undef LOADB1
#undef LOADB2
#undef FC1
#undef GELU_STORE
#undef FC2
}

// ---------------------------------------------------------------------------
extern "C" void kernel_launch(void* const* d_in, const int* in_sizes, int n_in,
                              void* d_out, int out_size, void* d_ws, size_t ws_size,
                              hipStream_t stream)
{
    const float* x    = (const float*)d_in[0];
    const float* ln1g = (const float*)d_in[1];
    const float* ln1b = (const float*)d_in[2];
    const float* ln2g = (const float*)d_in[3];
    const float* ln2b = (const float*)d_in[4];
    const float* w1   = (const float*)d_in[5];
    const float* b1   = (const float*)d_in[6];
    const float* w2   = (const float*)d_in[7];
    const float* b2   = (const float*)d_in[8];
    float* out = (float*)d_out;

    // workspace
    char* ws = (char*)d_ws;
    __hip_bfloat16* xnbuf = (__hip_bfloat16*)ws;                 //  67,108,864 B
    __hip_bfloat16* w1t   = (__hip_bfloat16*)(ws + 67108864);    //     524,288 B
    __hip_bfloat16* w2t   = (__hip_bfloat16*)(ws + 67633152);    //     524,288 B

    // weight transpose + bf16 convert (w1t[1024][256], w2t[256][1024])
    transpose_cvt<<<(CDIM * HDIM) / 256, 256, 0, stream>>>(w1, w1t, CDIM, HDIM);
    transpose_cvt<<<(CDIM * HDIM) / 256, 256, 0, stream>>>(w2, w2t, HDIM, CDIM);

    // fully fused block: 2048 blocks x 256 threads, 64 rows each, 2 blocks/CU
    swin_fused<<<M_TOTAL / 64, 256, 0, stream>>>(
        x, ln1g, ln1b, ln2g, ln2b, w1t, b1, w2t, b2, xnbuf, out);
}

// Round 9
// 358.486 us; speedup vs baseline: 1.1436x; 1.0093x over previous
//
#include <hip/hip_runtime.h>
#include <hip/hip_bf16.h>

#define M_TOTAL (32 * 64 * 64)   // 131072 rows
#define CDIM 256
#define HDIM 1024

typedef float  floatx4 __attribute__((ext_vector_type(4)));
typedef short  short8  __attribute__((ext_vector_type(8)));

// ---------------------------------------------------------------------------
// transpose + fp32->bf16 convert.  src[R][Cc] f32 -> dst[Cc][R] bf16
// ---------------------------------------------------------------------------
__global__ __launch_bounds__(256) void transpose_cvt(
    const float* __restrict__ src, __hip_bfloat16* __restrict__ dst,
    int R, int Cc)
{
    const int idx = blockIdx.x * 256 + threadIdx.x;   // idx = c*R + r
    const int r = idx % R;
    const int c = idx / R;
    dst[idx] = __float2bfloat16(src[(long)r * Cc + c]);
}

// fast GELU (tanh form), max dev vs erf-GELU ~1e-3 (validated R2-R8)
__device__ __forceinline__ float gelu_fast(float v)
{
    const float t = v * __builtin_fmaf(v * v, 0.044715f, 1.0f);
    const float e = __expf(t * -1.5957691216f);
    return v * __builtin_amdgcn_rcpf(1.0f + e);
}

// ---------------------------------------------------------------------------
// Fused Swin block, R9: 8 waves (1rg x 8cg), M-tile 64, LDS 64KB ->
// 2 blocks/CU = 16 waves/CU (R8 had 8).  Weight fragments loaded by
// inline-asm global_load_dwordx4 with COUNTED vmcnt waits (T4) so the
// compiler cannot sink them (R4-R8 failure).  Raw lgkmcnt-only barrier per
// chunk keeps b2f(c) in flight across it.
// Pipeline invariant per iter c (8 loads per burst):
//   enter: b2f(c-1) outstanding (8)
//   issue b1f(c) (8) -> vmcnt(8) => b2f(c-1) ready -> FC2(c-1)
//   vmcnt(0) => b1f(c) ready -> FC1(c) -> issue b2f(c) -> GELU -> barrier
// Frag conventions verified R1-R8: A/B k-map slot=kf*4+fq, elem k&7,
// row/col=fr; C/D col=lane&15, row=(lane>>4)*4+reg.
// ---------------------------------------------------------------------------
__global__ __launch_bounds__(512, 4) void swin_fused(
    const float* __restrict__ x,
    const float* __restrict__ ln1g, const float* __restrict__ ln1b,
    const float* __restrict__ ln2g, const float* __restrict__ ln2b,
    const __hip_bfloat16* __restrict__ w1t, const float* __restrict__ fb1,
    const __hip_bfloat16* __restrict__ w2t, const float* __restrict__ fb2,
    __hip_bfloat16* __restrict__ xnbuf, float* __restrict__ out)
{
    __shared__ __align__(16) __hip_bfloat16 As[16384];      // 32 KB
    __shared__ __align__(16) __hip_bfloat16 Hs[2][8192];    // 2 x 16 KB

    const int  tid = threadIdx.x;
    const long m0  = (long)blockIdx.x * 64;

    // ---------------- LN phase: 8 threads per row ----------------
    {
        const int row  = tid >> 3;        // 0..63
        const int part = tid & 7;         // 32-element segment
        const float* xr = x + (m0 + row) * CDIM + part * 32;

        float4 v[8];
        float s = 0.f, sq = 0.f;
#pragma unroll
        for (int i = 0; i < 8; ++i) {
            v[i] = ((const float4*)xr)[i];
            s  += v[i].x + v[i].y + v[i].z + v[i].w;
            sq += v[i].x*v[i].x + v[i].y*v[i].y + v[i].z*v[i].z + v[i].w*v[i].w;
        }
        s  += __shfl_xor(s, 1);  s  += __shfl_xor(s, 2);  s  += __shfl_xor(s, 4);
        sq += __shfl_xor(sq, 1); sq += __shfl_xor(sq, 2); sq += __shfl_xor(sq, 4);
        const float mu = s * (1.f / CDIM);
        const float rs = rsqrtf(sq * (1.f / CDIM) - mu * mu + 1e-5f);

        float s2 = 0.f, q2 = 0.f;
        __hip_bfloat16* xnp = xnbuf + (m0 + row) * CDIM + part * 32;
#pragma unroll
        for (int i = 0; i < 8; ++i) {
            const float4 G = ((const float4*)(ln1g + part * 32))[i];
            const float4 B = ((const float4*)(ln1b + part * 32))[i];
            v[i].x += (v[i].x - mu) * rs * G.x + B.x;
            v[i].y += (v[i].y - mu) * rs * G.y + B.y;
            v[i].z += (v[i].z - mu) * rs * G.z + B.z;
            v[i].w += (v[i].w - mu) * rs * G.w + B.w;
            s2 += v[i].x + v[i].y + v[i].z + v[i].w;
            q2 += v[i].x*v[i].x + v[i].y*v[i].y + v[i].z*v[i].z + v[i].w*v[i].w;
            union { ushort4 u; __hip_bfloat16 h[4]; } p;
            p.h[0] = __float2bfloat16(v[i].x); p.h[1] = __float2bfloat16(v[i].y);
            p.h[2] = __float2bfloat16(v[i].z); p.h[3] = __float2bfloat16(v[i].w);
            ((ushort4*)xnp)[i] = p.u;
        }
        s2 += __shfl_xor(s2, 1); s2 += __shfl_xor(s2, 2); s2 += __shfl_xor(s2, 4);
        q2 += __shfl_xor(q2, 1); q2 += __shfl_xor(q2, 2); q2 += __shfl_xor(q2, 4);
        const float mu2 = s2 * (1.f / CDIM);
        const float rs2 = rsqrtf(q2 * (1.f / CDIM) - mu2 * mu2 + 1e-5f);

        // ln2 -> As fragment layout: slot=(k>>5)*4+((k>>3)&3), elem k&7
#pragma unroll
        for (int i = 0; i < 8; ++i) {
            const int col0 = part * 32 + i * 4;
            const float4 G = ((const float4*)(ln2g + part * 32))[i];
            const float4 B = ((const float4*)(ln2b + part * 32))[i];
            union { ushort4 u; __hip_bfloat16 h[4]; } p;
            p.h[0] = __float2bfloat16((v[i].x - mu2) * rs2 * G.x + B.x);
            p.h[1] = __float2bfloat16((v[i].y - mu2) * rs2 * G.y + B.y);
            p.h[2] = __float2bfloat16((v[i].z - mu2) * rs2 * G.z + B.z);
            p.h[3] = __float2bfloat16((v[i].w - mu2) * rs2 * G.w + B.w);
            const int idx16 = ((col0 >> 5) * 4 + ((col0 >> 3) & 3)) * 64 + row;
            *(ushort4*)(As + idx16 * 8 + (col0 & 7)) = p.u;
        }
    }

    // ---------------- MLP ids + preloads (before the barrier) -------------
    const int wn = tid >> 6;            // wave 0..7 = col-group
    const int lane = tid & 63;
    const int fr = lane & 15, fq = lane >> 4;

    float fb1w[8];
#pragma unroll
    for (int c = 0; c < 8; ++c) fb1w[c] = fb1[c * 128 + wn * 16 + fr];
    float fb2w[2];
#pragma unroll
    for (int nf = 0; nf < 2; ++nf) fb2w[nf] = fb2[wn * 32 + nf * 16 + fr];

    const __hip_bfloat16* w1p = w1t + (wn * 16 + fr) * 256 + fq * 8;
    const __hip_bfloat16* w2p = w2t + (wn * 32 + fr) * 1024 + fq * 8;

    short8 b1f[8];        // fc1 frags (kf 0..7), 32 VGPR
    short8 b2f[4][2];     // fc2 frags [kf][nf], 32 VGPR
    floatx4 acc1[4];
    floatx4 acc2[4][2] = {};

#define ISSUE_B1(c)                                                           \
    { _Pragma("unroll")                                                       \
      for (int kf = 0; kf < 8; ++kf)                                          \
          asm volatile("global_load_dwordx4 %0, %1, off"                      \
              : "=&v"(b1f[kf]) : "v"(w1p + (c) * 32768 + kf * 32)); }
#define ISSUE_B2(c)                                                           \
    { _Pragma("unroll")                                                       \
      for (int kf = 0; kf < 4; ++kf)                                          \
          _Pragma("unroll")                                                   \
          for (int nf = 0; nf < 2; ++nf)                                      \
              asm volatile("global_load_dwordx4 %0, %1, off"                  \
                  : "=&v"(b2f[kf][nf])                                        \
                  : "v"(w2p + (c) * 128 + nf * 16384 + kf * 32)); }
#define WAIT8()  { asm volatile("s_waitcnt vmcnt(8)");                        \
                   __builtin_amdgcn_sched_barrier(0); }
#define WAIT0()  { asm volatile("s_waitcnt vmcnt(0)");                        \
                   __builtin_amdgcn_sched_barrier(0); }
#define BARRIER_LGKM() asm volatile("s_waitcnt lgkmcnt(0)\n\ts_barrier" ::: "memory")

    // fc1: rows 0..63 (mf=4), chunk col wn*16+fr (nf=1), K=256 (kf=8)
#define FC1(c)                                                                \
    { _Pragma("unroll")                                                       \
      for (int mf = 0; mf < 4; ++mf) acc1[mf] = (floatx4){0.f,0.f,0.f,0.f};   \
      _Pragma("unroll")                                                       \
      for (int kf = 0; kf < 8; ++kf) {                                        \
          short8 a[4];                                                        \
          _Pragma("unroll")                                                   \
          for (int mf = 0; mf < 4; ++mf)                                      \
              a[mf] = *(const short8*)(                                       \
                  As + ((kf * 4 + fq) * 64 + mf * 16 + fr) * 8);              \
          _Pragma("unroll")                                                   \
          for (int mf = 0; mf < 4; ++mf)                                      \
              acc1[mf] = __builtin_amdgcn_mfma_f32_16x16x32_bf16(             \
                  a[mf], b1f[kf], acc1[mf], 0, 0, 0);                         \
      } }

#define GELU_STORE(c)                                                         \
    { __hip_bfloat16* hb = Hs[(c) & 1];                                       \
      const int   col = wn * 16 + fr;                                         \
      const float bb  = fb1w[c];                                              \
      __hip_bfloat16* hp =                                                    \
          hb + (((col >> 5) * 4 + ((col >> 3) & 3)) * 64) * 8 + (col & 7);    \
      _Pragma("unroll")                                                       \
      for (int mf = 0; mf < 4; ++mf)                                          \
          _Pragma("unroll")                                                   \
          for (int j = 0; j < 4; ++j) {                                       \
              const int row = mf * 16 + fq * 4 + j;                           \
              hp[row * 8] = __float2bfloat16(gelu_fast(acc1[mf][j] + bb));    \
          } }

    // fc2: rows 0..63 (mf=4), out cols wn*32+nf*16 (nf=2), chunk K=128 (kf=4)
#define FC2(c)                                                                \
    { const __hip_bfloat16* hb = Hs[(c) & 1];                                 \
      _Pragma("unroll")                                                       \
      for (int kf = 0; kf < 4; ++kf) {                                        \
          short8 ha[4];                                                       \
          _Pragma("unroll")                                                   \
          for (int mf = 0; mf < 4; ++mf)                                      \
              ha[mf] = *(const short8*)(                                      \
                  hb + ((kf * 4 + fq) * 64 + mf * 16 + fr) * 8);              \
          _Pragma("unroll")                                                   \
          for (int mf = 0; mf < 4; ++mf)                                      \
              _Pragma("unroll")                                               \
              for (int nf = 0; nf < 2; ++nf)                                  \
                  acc2[mf][nf] = __builtin_amdgcn_mfma_f32_16x16x32_bf16(     \
                      ha[mf], b2f[kf][nf], acc2[mf][nf], 0, 0, 0);            \
      } }

    ISSUE_B1(0);           // drained by __syncthreads' vmcnt(0) — free prologue
    __syncthreads();       // As visible; all prologue VMEM retired

    WAIT0(); FC1(0);
    ISSUE_B2(0);
    GELU_STORE(0);
    BARRIER_LGKM();        // b2f(0) stays in flight

#pragma unroll
    for (int c = 1; c < 8; ++c) {
        ISSUE_B1(c);       // outstanding: b2f(c-1)=8 old + b1f(c)=8 new
        WAIT8();           // b2f(c-1) ready
        FC2(c - 1);
        WAIT0();           // b1f(c) ready
        FC1(c);
        ISSUE_B2(c);       // hides under GELU + barrier + next FC2
        GELU_STORE(c);
        BARRIER_LGKM();
    }
    WAIT0();               // b2f(7) ready
    FC2(7);

    // ---------------- epilogue: out = acc2 + b2 + xn ----------------
#pragma unroll
    for (int nf = 0; nf < 2; ++nf) {
        const int oc = wn * 32 + nf * 16 + fr;
#pragma unroll
        for (int mf = 0; mf < 4; ++mf)
#pragma unroll
            for (int j = 0; j < 4; ++j) {
                const long row = m0 + mf * 16 + fq * 4 + j;
                out[row * CDIM + oc] = acc2[mf][nf][j] + fb2w[nf]
                                     + __bfloat162float(xnbuf[row * CDIM + oc]);
            }
    }
#undef ISSUE_B1
#undef ISSUE_B2
#undef WAIT8
#undef WAIT0
#undef BARRIER_LGKM
#undef FC1
#undef GELU_STORE
#undef FC2
}

// ---------------------------------------------------------------------------
extern "C" void kernel_launch(void* const* d_in, const int* in_sizes, int n_in,
                              void* d_out, int out_size, void* d_ws, size_t ws_size,
                              hipStream_t stream)
{
    const float* x    = (const float*)d_in[0];
    const float* ln1g = (const float*)d_in[1];
    const float* ln1b = (const float*)d_in[2];
    const float* ln2g = (const float*)d_in[3];
    const float* ln2b = (const float*)d_in[4];
    const float* w1   = (const float*)d_in[5];
    const float* b1   = (const float*)d_in[6];
    const float* w2   = (const float*)d_in[7];
    const float* b2   = (const float*)d_in[8];
    float* out = (float*)d_out;

    // workspace
    char* ws = (char*)d_ws;
    __hip_bfloat16* xnbuf = (__hip_bfloat16*)ws;                 //  67,108,864 B
    __hip_bfloat16* w1t   = (__hip_bfloat16*)(ws + 67108864);    //     524,288 B
    __hip_bfloat16* w2t   = (__hip_bfloat16*)(ws + 67633152);    //     524,288 B

    // weight transpose + bf16 convert (w1t[1024][256], w2t[256][1024])
    transpose_cvt<<<(CDIM * HDIM) / 256, 256, 0, stream>>>(w1, w1t, CDIM, HDIM);
    transpose_cvt<<<(CDIM * HDIM) / 256, 256, 0, stream>>>(w2, w2t, HDIM, CDIM);

    // fused block: 2048 blocks x 512 threads, 64 rows each, 2 blocks/CU
    swin_fused<<<M_TOTAL / 64, 512, 0, stream>>>(
        x, ln1g, ln1b, ln2g, ln2b, w1t, b1, w2t, b2, xnbuf, out);
}